// Round 4
// baseline (602.122 us; speedup 1.0000x reference)
//
#include <hip/hip_runtime.h>

// DualBiPlane, locality-sorted pipeline.
//
// R1-R3 showed the naive per-point kernel is bound by random gathers: 769 MB
// of HBM fetch vs 82 MB of plane data (random access over 82 MB >> 4 MB/XCD
// L2, plus 128B-line amplification). Fix: counting-sort points into
// (m, i>>3, j>>3) bins so consecutive points gather from a ~5 KB region
// (L1-resident). xy and uv coords are independent -> two record streams,
// two interp passes, each writing its 64B half of out[p].
//
// Kernels: memset(hist) -> k_hist (dual histogram, global atomics)
//          -> k_scan (single block, both hists) -> k_scatter (dual, 16B recs)
//          -> k_interp(recA, Fxy, half 0) -> k_interp(recB, Fuv, half 16).
// Deterministic: record order within a bin is atomic-dependent, but each
// record carries its own p and per-point work is independent.

typedef float f32x4 __attribute__((ext_vector_type(4)));

constexpr int RES = 400;                        // HX = HY = U_RES = V_RES
constexpr int LCH = 16;                         // LXY = LUV
constexpr long long PLANE_STRIDE = (long long)RES * RES * LCH;
constexpr int SB = 3;                           // 8x8 texel bins
constexpr int BPL = RES >> SB;                  // 50 bins per axis
constexpr int BINS_PER_M = BPL * BPL;           // 2500
constexpr int NBINS = 4 * BINS_PER_M;           // 10000
constexpr int SCAN_THREADS = 1024;
constexpr int BINS_PER_THREAD = (NBINS + SCAN_THREADS - 1) / SCAN_THREADS; // 10

// ws layout (byte offsets)
constexpr size_t OFF_A   = 0;
constexpr size_t OFF_B   = 40960;
constexpr size_t HIST_A  = 81920;
constexpr size_t HIST_B  = 122880;
constexpr size_t REC_A   = 262144;              // 16B-aligned

__device__ __forceinline__ float edge(float f) {
    return (f == (float)RES) ? (float)(RES - 1) : f;   // where(ind==RES, RES-1, ind)
}

__global__ __launch_bounds__(256) void k_hist(
    const int* __restrict__ mArr, const float* __restrict__ h,
    const float* __restrict__ u, const float* __restrict__ v,
    int* __restrict__ histA, int* __restrict__ histB, int N)
{
    int p = blockIdx.x * 256 + threadIdx.x;
    if (p >= N) return;
    int m = mArr[p];
    float fi = edge((h[2*p]   + 1.0f) * 0.5f * (float)RES);
    float fj = edge((h[2*p+1] + 1.0f) * 0.5f * (float)RES);
    atomicAdd(&histA[m*BINS_PER_M + (((int)fi)>>SB)*BPL + (((int)fj)>>SB)], 1);
    float gi = edge(u[p] * (float)RES);
    float gj = edge(v[p] * (float)RES);
    atomicAdd(&histB[m*BINS_PER_M + (((int)gi)>>SB)*BPL + (((int)gj)>>SB)], 1);
}

__global__ __launch_bounds__(SCAN_THREADS) void k_scan(
    const int* __restrict__ histA, int* __restrict__ offA,
    const int* __restrict__ histB, int* __restrict__ offB)
{
    __shared__ int sums[SCAN_THREADS];
    for (int pass = 0; pass < 2; ++pass) {
        const int* hist = pass ? histB : histA;
        int* off        = pass ? offB  : offA;
        int t = threadIdx.x;
        int local[BINS_PER_THREAD];
        int s = 0;
        #pragma unroll
        for (int k = 0; k < BINS_PER_THREAD; ++k) {
            int b = t * BINS_PER_THREAD + k;
            local[k] = s;
            if (b < NBINS) s += hist[b];
        }
        sums[t] = s;
        __syncthreads();
        int inc = s;
        for (int d = 1; d < SCAN_THREADS; d <<= 1) {
            int val = (t >= d) ? sums[t - d] : 0;
            __syncthreads();
            sums[t] += val;
            __syncthreads();
        }
        int exc = sums[t] - inc;   // exclusive prefix of this thread's chunk
        #pragma unroll
        for (int k = 0; k < BINS_PER_THREAD; ++k) {
            int b = t * BINS_PER_THREAD + k;
            if (b < NBINS) off[b] = exc + local[k];
        }
        __syncthreads();
    }
}

__global__ __launch_bounds__(256) void k_scatter(
    const int* __restrict__ mArr, const float* __restrict__ h,
    const float* __restrict__ u, const float* __restrict__ v,
    int* __restrict__ offA, int* __restrict__ offB,
    f32x4* __restrict__ recA, f32x4* __restrict__ recB, int N)
{
    int p = blockIdx.x * 256 + threadIdx.x;
    if (p >= N) return;
    int m = __builtin_nontemporal_load(mArr + p);
    unsigned pm = (unsigned)p | ((unsigned)m << 24);

    float hx = __builtin_nontemporal_load(h + 2*p);
    float hy = __builtin_nontemporal_load(h + 2*p + 1);
    float fi = edge((hx + 1.0f) * 0.5f * (float)RES);
    float fj = edge((hy + 1.0f) * 0.5f * (float)RES);
    int binA = m*BINS_PER_M + (((int)fi)>>SB)*BPL + (((int)fj)>>SB);
    int posA = atomicAdd(&offA[binA], 1);
    f32x4 rA; rA.x = fi; rA.y = fj; rA.z = __int_as_float((int)pm); rA.w = 0.0f;
    recA[posA] = rA;

    float gi = edge(__builtin_nontemporal_load(u + p) * (float)RES);
    float gj = edge(__builtin_nontemporal_load(v + p) * (float)RES);
    int binB = m*BINS_PER_M + (((int)gi)>>SB)*BPL + (((int)gj)>>SB);
    int posB = atomicAdd(&offB[binB], 1);
    f32x4 rB; rB.x = gi; rB.y = gj; rB.z = __int_as_float((int)pm); rB.w = 0.0f;
    recB[posB] = rB;
}

// 4 lanes per record; lane c handles channels c*4..c*4+3.
__global__ __launch_bounds__(256) void k_interp(
    const f32x4* __restrict__ rec, const float* __restrict__ F,
    float* __restrict__ out, int halfOfs, int N)
{
    long long t = (long long)blockIdx.x * 256 + threadIdx.x;
    int q = (int)(t >> 2);
    if (q >= N) return;
    int c = (int)(t & 3);

    f32x4 r = rec[q];
    float fi = r.x, fj = r.y;
    unsigned pm = __float_as_uint(r.z);
    int p = (int)(pm & 0xFFFFFFu);
    int m = (int)(pm >> 24);

    int i1 = (int)fi, j1 = (int)fj;
    float ir = fi - (float)i1, jr = fj - (float)j1;
    int i2 = (i1 + 1 == RES) ? 0 : i1 + 1;
    int j2 = (j1 + 1 == RES) ? 0 : j1 + 1;

    const float* __restrict__ Fb = F + (long long)m * PLANE_STRIDE + c * 4;
    f32x4 g00 = *reinterpret_cast<const f32x4*>(Fb + (i1 * RES + j1) * LCH);
    f32x4 g10 = *reinterpret_cast<const f32x4*>(Fb + (i2 * RES + j1) * LCH);
    f32x4 g01 = *reinterpret_cast<const f32x4*>(Fb + (i1 * RES + j2) * LCH);
    f32x4 g11 = *reinterpret_cast<const f32x4*>(Fb + (i2 * RES + j2) * LCH);

    float omi = 1.0f - ir, omj = 1.0f - jr;
    f32x4 res = (g00 * omi + g10 * ir) * omj + (g01 * omi + g11 * ir) * jr;

    __builtin_nontemporal_store(res,
        reinterpret_cast<f32x4*>(out + (long long)p * 32 + halfOfs + c * 4));
}

// Fallback (R3 kernel) if ws is too small for the sort pipeline.
__global__ __launch_bounds__(256) void dualbiplane_simple(
    const int* __restrict__ mArr, const float* __restrict__ h,
    const float* __restrict__ u, const float* __restrict__ v,
    const float* __restrict__ Fxy, const float* __restrict__ Fuv,
    float* __restrict__ out, int N)
{
    long long t = (long long)blockIdx.x * blockDim.x + threadIdx.x;
    int p = (int)(t >> 3);
    if (p >= N) return;
    int sub = (int)(t & 7);
    int mi = mArr[p];
    float fi, fj;
    const float* __restrict__ F;
    if (sub < 4) {
        fi = edge((h[2ll*p]   + 1.0f) * 0.5f * (float)RES);
        fj = edge((h[2ll*p+1] + 1.0f) * 0.5f * (float)RES);
        F = Fxy;
    } else {
        fi = edge(u[p] * (float)RES);
        fj = edge(v[p] * (float)RES);
        F = Fuv;
    }
    int i1 = (int)fi, j1 = (int)fj;
    float ir = fi - (float)i1, jr = fj - (float)j1;
    int i2 = (i1 + 1 == RES) ? 0 : i1 + 1;
    int j2 = (j1 + 1 == RES) ? 0 : j1 + 1;
    int c = (sub & 3) * 4;
    const float* __restrict__ Fb = F + (long long)mi * PLANE_STRIDE + c;
    f32x4 g00 = *reinterpret_cast<const f32x4*>(Fb + (i1 * RES + j1) * LCH);
    f32x4 g10 = *reinterpret_cast<const f32x4*>(Fb + (i2 * RES + j1) * LCH);
    f32x4 g01 = *reinterpret_cast<const f32x4*>(Fb + (i1 * RES + j2) * LCH);
    f32x4 g11 = *reinterpret_cast<const f32x4*>(Fb + (i2 * RES + j2) * LCH);
    float omi = 1.0f - ir, omj = 1.0f - jr;
    f32x4 res = (g00 * omi + g10 * ir) * omj + (g01 * omi + g11 * ir) * jr;
    __builtin_nontemporal_store(res, reinterpret_cast<f32x4*>(out + t * 4));
}

extern "C" void kernel_launch(void* const* d_in, const int* in_sizes, int n_in,
                              void* d_out, int out_size, void* d_ws, size_t ws_size,
                              hipStream_t stream)
{
    const int*   m   = (const int*)d_in[0];
    const float* h   = (const float*)d_in[1];
    const float* u   = (const float*)d_in[2];
    const float* v   = (const float*)d_in[3];
    const float* Fxy = (const float*)d_in[4];
    const float* Fuv = (const float*)d_in[5];
    float* out = (float*)d_out;
    int N = in_sizes[0];

    size_t need = REC_A + 2ull * (size_t)N * 16ull;
    if (ws_size < need) {
        long long total = (long long)N * 8;
        dualbiplane_simple<<<(unsigned)((total + 255) / 256), 256, 0, stream>>>(
            m, h, u, v, Fxy, Fuv, out, N);
        return;
    }

    char* ws = (char*)d_ws;
    int*   offA  = (int*)(ws + OFF_A);
    int*   offB  = (int*)(ws + OFF_B);
    int*   histA = (int*)(ws + HIST_A);
    int*   histB = (int*)(ws + HIST_B);
    f32x4* recA  = (f32x4*)(ws + REC_A);
    f32x4* recB  = recA + N;

    hipMemsetAsync(ws + HIST_A, 0, 2 * 40960, stream);

    int blocksP = (N + 255) / 256;
    k_hist<<<blocksP, 256, 0, stream>>>(m, h, u, v, histA, histB, N);
    k_scan<<<1, SCAN_THREADS, 0, stream>>>(histA, offA, histB, offB);
    k_scatter<<<blocksP, 256, 0, stream>>>(m, h, u, v, offA, offB, recA, recB, N);

    long long tot4 = (long long)N * 4;
    unsigned blocksI = (unsigned)((tot4 + 255) / 256);
    k_interp<<<blocksI, 256, 0, stream>>>(recA, Fxy, out, 0,  N);
    k_interp<<<blocksI, 256, 0, stream>>>(recB, Fuv, out, 16, N);
}

// Round 5
// 244.534 us; speedup vs baseline: 2.4623x; 2.4623x over previous
//
#include <hip/hip_runtime.h>

// DualBiPlane, fp16-compressed-plane version.
//
// R1-R3: naive kernel = 270 us, bound by ~769 MB of L2-miss gather traffic
// at ~3.9 TB/s effective (random 64-128B granules over an 82 MB working set
// vs 32 MB aggregate L2). R4's counting sort regressed (scatter write
// amplification, 602 us) - reverted.
//
// R5: convert Fxy/Fuv f32 -> fp16 into d_ws each launch (streaming, ~20 us),
// then gather 32B fp16 corners: halves gather line traffic AND the 41 MB
// working set ~fits aggregate L2 -> hit rate up. fp16 RTN adds <=~0.003 abs
// error (threshold 0.098). Output stores stay nt so the 268 MB write stream
// doesn't evict the planes.

typedef float f32x4 __attribute__((ext_vector_type(4)));
typedef _Float16 f16;
typedef f16 f16x4 __attribute__((ext_vector_type(4)));
typedef f16 f16x8 __attribute__((ext_vector_type(8)));

constexpr int RES = 400;                        // HX = HY = U_RES = V_RES
constexpr int LCH = 16;                         // LXY = LUV
constexpr long long PLANE_STRIDE = (long long)RES * RES * LCH;  // per-m elems
constexpr long long PLANE_ELEMS  = 4 * PLANE_STRIDE;            // 10.24M per family

__device__ __forceinline__ float edge(float f) {
    return (f == (float)RES) ? (float)(RES - 1) : f;   // where(ind==RES, RES-1, ind)
}

// f32 -> fp16 plane conversion, 8 elems/thread.
__global__ __launch_bounds__(256) void k_conv(
    const float* __restrict__ src, f16* __restrict__ dst, long long n)
{
    long long i = ((long long)blockIdx.x * 256 + threadIdx.x) * 8;
    if (i >= n) return;
    f32x4 a, b;
    a.x = __builtin_nontemporal_load(src + i);
    a.y = __builtin_nontemporal_load(src + i + 1);
    a.z = __builtin_nontemporal_load(src + i + 2);
    a.w = __builtin_nontemporal_load(src + i + 3);
    b.x = __builtin_nontemporal_load(src + i + 4);
    b.y = __builtin_nontemporal_load(src + i + 5);
    b.z = __builtin_nontemporal_load(src + i + 6);
    b.w = __builtin_nontemporal_load(src + i + 7);
    f16x8 r;
    r[0] = (f16)a.x; r[1] = (f16)a.y; r[2] = (f16)a.z; r[3] = (f16)a.w;
    r[4] = (f16)b.x; r[5] = (f16)b.y; r[6] = (f16)b.z; r[7] = (f16)b.w;
    *reinterpret_cast<f16x8*>(dst + i) = r;     // plain store: keep in cache
}

// 8 lanes per point: sub<4 -> Fxy (channels sub*4..+3), sub>=4 -> Fuv.
__global__ __launch_bounds__(256) void dualbiplane_f16(
    const int* __restrict__ mArr,
    const float* __restrict__ h,
    const float* __restrict__ u,
    const float* __restrict__ v,
    const f16* __restrict__ Fxy,
    const f16* __restrict__ Fuv,
    float* __restrict__ out,
    int N)
{
    long long t = (long long)blockIdx.x * blockDim.x + threadIdx.x;
    int p = (int)(t >> 3);
    if (p >= N) return;
    int sub = (int)(t & 7);

    int mi = __builtin_nontemporal_load(mArr + p);

    float fi, fj;
    const f16* __restrict__ F;
    if (sub < 4) {
        float hx = __builtin_nontemporal_load(h + 2ll * p);
        float hy = __builtin_nontemporal_load(h + 2ll * p + 1);
        fi = (hx + 1.0f) * 0.5f * (float)RES;
        fj = (hy + 1.0f) * 0.5f * (float)RES;
        F = Fxy;
    } else {
        fi = __builtin_nontemporal_load(u + p) * (float)RES;
        fj = __builtin_nontemporal_load(v + p) * (float)RES;
        F = Fuv;
    }
    fi = edge(fi);
    fj = edge(fj);

    int i1 = (int)fi, j1 = (int)fj;
    float ir = fi - (float)i1, jr = fj - (float)j1;
    int i2 = (i1 + 1 == RES) ? 0 : i1 + 1;
    int j2 = (j1 + 1 == RES) ? 0 : j1 + 1;

    int c = (sub & 3) * 4;
    const f16* __restrict__ Fb = F + (long long)mi * PLANE_STRIDE + c;

    f16x4 h00 = *reinterpret_cast<const f16x4*>(Fb + (i1 * RES + j1) * LCH);
    f16x4 h10 = *reinterpret_cast<const f16x4*>(Fb + (i2 * RES + j1) * LCH);
    f16x4 h01 = *reinterpret_cast<const f16x4*>(Fb + (i1 * RES + j2) * LCH);
    f16x4 h11 = *reinterpret_cast<const f16x4*>(Fb + (i2 * RES + j2) * LCH);

    float omi = 1.0f - ir, omj = 1.0f - jr;
    f32x4 r;
    #pragma unroll
    for (int k = 0; k < 4; ++k) {
        float g00 = (float)h00[k], g10 = (float)h10[k];
        float g01 = (float)h01[k], g11 = (float)h11[k];
        r[k] = (g00 * omi + g10 * ir) * omj + (g01 * omi + g11 * ir) * jr;
    }

    __builtin_nontemporal_store(r, reinterpret_cast<f32x4*>(out + t * 4));
}

// Fallback (R3 kernel, f32 planes) if ws is too small.
__global__ __launch_bounds__(256) void dualbiplane_simple(
    const int* __restrict__ mArr, const float* __restrict__ h,
    const float* __restrict__ u, const float* __restrict__ v,
    const float* __restrict__ Fxy, const float* __restrict__ Fuv,
    float* __restrict__ out, int N)
{
    long long t = (long long)blockIdx.x * blockDim.x + threadIdx.x;
    int p = (int)(t >> 3);
    if (p >= N) return;
    int sub = (int)(t & 7);
    int mi = mArr[p];
    float fi, fj;
    const float* __restrict__ F;
    if (sub < 4) {
        fi = edge((h[2ll*p]   + 1.0f) * 0.5f * (float)RES);
        fj = edge((h[2ll*p+1] + 1.0f) * 0.5f * (float)RES);
        F = Fxy;
    } else {
        fi = edge(u[p] * (float)RES);
        fj = edge(v[p] * (float)RES);
        F = Fuv;
    }
    int i1 = (int)fi, j1 = (int)fj;
    float ir = fi - (float)i1, jr = fj - (float)j1;
    int i2 = (i1 + 1 == RES) ? 0 : i1 + 1;
    int j2 = (j1 + 1 == RES) ? 0 : j1 + 1;
    int c = (sub & 3) * 4;
    const float* __restrict__ Fb = F + (long long)mi * PLANE_STRIDE + c;
    f32x4 g00 = *reinterpret_cast<const f32x4*>(Fb + (i1 * RES + j1) * LCH);
    f32x4 g10 = *reinterpret_cast<const f32x4*>(Fb + (i2 * RES + j1) * LCH);
    f32x4 g01 = *reinterpret_cast<const f32x4*>(Fb + (i1 * RES + j2) * LCH);
    f32x4 g11 = *reinterpret_cast<const f32x4*>(Fb + (i2 * RES + j2) * LCH);
    float omi = 1.0f - ir, omj = 1.0f - jr;
    f32x4 res = (g00 * omi + g10 * ir) * omj + (g01 * omi + g11 * ir) * jr;
    __builtin_nontemporal_store(res, reinterpret_cast<f32x4*>(out + t * 4));
}

extern "C" void kernel_launch(void* const* d_in, const int* in_sizes, int n_in,
                              void* d_out, int out_size, void* d_ws, size_t ws_size,
                              hipStream_t stream)
{
    const int*   m   = (const int*)d_in[0];
    const float* h   = (const float*)d_in[1];
    const float* u   = (const float*)d_in[2];
    const float* v   = (const float*)d_in[3];
    const float* Fxy = (const float*)d_in[4];
    const float* Fuv = (const float*)d_in[5];
    float* out = (float*)d_out;
    int N = in_sizes[0];

    size_t need = 2ull * PLANE_ELEMS * sizeof(f16);   // ~41 MB
    if (ws_size < need) {
        long long total = (long long)N * 8;
        dualbiplane_simple<<<(unsigned)((total + 255) / 256), 256, 0, stream>>>(
            m, h, u, v, Fxy, Fuv, out, N);
        return;
    }

    f16* Fxy16 = (f16*)d_ws;
    f16* Fuv16 = Fxy16 + PLANE_ELEMS;

    unsigned convBlocks = (unsigned)((PLANE_ELEMS / 8 + 255) / 256);
    k_conv<<<convBlocks, 256, 0, stream>>>(Fxy, Fxy16, PLANE_ELEMS);
    k_conv<<<convBlocks, 256, 0, stream>>>(Fuv, Fuv16, PLANE_ELEMS);

    long long total = (long long)N * 8;
    dualbiplane_f16<<<(unsigned)((total + 255) / 256), 256, 0, stream>>>(
        m, h, u, v, Fxy16, Fuv16, out, N);
}

// Round 6
// 197.309 us; speedup vs baseline: 3.0517x; 1.2393x over previous
//
#include <hip/hip_runtime.h>

// DualBiPlane R6: fp16 planes + cheap 16-bin counting sort for L2 locality.
//
// R5 analysis: interp FETCH 613 MB ~= the no-reuse floor (512 MB useful corner
// bytes) -> caches capture no reuse (random over 41 MB >> 4 MB/XCD L2).
// Fix: group point-plane records by (m, i>>7): 16 bins/family, 1.64 MB fp16
// footprint each -> bin-resident in every XCD L2 as blocks sweep bins in
// dispatch order. 8B records; block-aggregated scatter (LDS hist + 1 global
// atomic/bin/block) to avoid R4's write-amplification disaster.

typedef float f32x4 __attribute__((ext_vector_type(4)));
typedef _Float16 f16;
typedef f16 f16x4 __attribute__((ext_vector_type(4)));
typedef f16 f16x8 __attribute__((ext_vector_type(8)));
typedef unsigned int u32;
typedef unsigned long long u64;

constexpr int RES = 400;
constexpr int LCH = 16;
constexpr long long PLANE_STRIDE = (long long)RES * RES * LCH;   // elems per m
constexpr long long PLANE_ELEMS  = 4 * PLANE_STRIDE;             // per family

constexpr int NSLICE = 4;             // i1 >> 7
constexpr int BINS_F = 4 * NSLICE;    // 16 bins per family
constexpr int NBINS  = 2 * BINS_F;    // 32 total (A: 0..15, B: 16..31)
constexpr int PTS_PER_BLOCK = 1024;   // 256 threads x 4 points

constexpr size_t PLANES_BYTES = (size_t)(2 * PLANE_ELEMS) * sizeof(f16); // 40.96 MB

__device__ __forceinline__ float edge(float f) {
    return (f == (float)RES) ? (float)(RES - 1) : f;
}

// quantize coords to 11-bit fixed point fraction; qi < 2^20
__device__ __forceinline__ u32 quant(float f) { return (u32)(edge(f) * 2048.0f); }

__device__ __forceinline__ u64 pack_rec(u32 qi, u32 qj, int p, int m) {
    return (u64)qi | ((u64)qj << 20) | ((u64)((u32)p | ((u32)m << 21)) << 40);
}

// ---------------- conv: f32 plane -> fp16 plane ----------------
__global__ __launch_bounds__(256) void k_conv(
    const float* __restrict__ src, f16* __restrict__ dst, long long n)
{
    long long i = ((long long)blockIdx.x * 256 + threadIdx.x) * 8;
    if (i >= n) return;
    f32x4 a, b;
    a.x = __builtin_nontemporal_load(src + i);
    a.y = __builtin_nontemporal_load(src + i + 1);
    a.z = __builtin_nontemporal_load(src + i + 2);
    a.w = __builtin_nontemporal_load(src + i + 3);
    b.x = __builtin_nontemporal_load(src + i + 4);
    b.y = __builtin_nontemporal_load(src + i + 5);
    b.z = __builtin_nontemporal_load(src + i + 6);
    b.w = __builtin_nontemporal_load(src + i + 7);
    f16x8 r;
    r[0] = (f16)a.x; r[1] = (f16)a.y; r[2] = (f16)a.z; r[3] = (f16)a.w;
    r[4] = (f16)b.x; r[5] = (f16)b.y; r[6] = (f16)b.z; r[7] = (f16)b.w;
    *reinterpret_cast<f16x8*>(dst + i) = r;
}

// ---------------- hist ----------------
__global__ __launch_bounds__(256) void k_hist(
    const int* __restrict__ mArr, const float* __restrict__ h,
    const float* __restrict__ u, const float* __restrict__ v,
    u32* __restrict__ histG, int N)
{
    __shared__ u32 lh[NBINS];
    if (threadIdx.x < NBINS) lh[threadIdx.x] = 0;
    __syncthreads();
    int base = blockIdx.x * PTS_PER_BLOCK;
    #pragma unroll
    for (int k = 0; k < 4; ++k) {
        int p = base + threadIdx.x + k * 256;
        if (p < N) {
            int m = mArr[p];
            float hx = h[2ll * p], hy = h[2ll * p + 1];
            u32 qi = quant((hx + 1.0f) * 0.5f * (float)RES);
            (void)quant((hy + 1.0f) * 0.5f * (float)RES);
            atomicAdd(&lh[m * NSLICE + (qi >> 18)], 1u);
            u32 gi = quant(u[p] * (float)RES);
            atomicAdd(&lh[BINS_F + m * NSLICE + (gi >> 18)], 1u);
        }
    }
    __syncthreads();
    if (threadIdx.x < NBINS) atomicAdd(&histG[threadIdx.x], lh[threadIdx.x]);
}

// ---------------- scan: 32 bins, two independent prefix groups ----------------
__global__ void k_scan(const u32* __restrict__ histG, u32* __restrict__ cursor)
{
    if (threadIdx.x == 0) {
        u32 off = 0;
        for (int b = 0; b < BINS_F; ++b) { cursor[b] = off; off += histG[b]; }
        off = 0;
        for (int b = BINS_F; b < NBINS; ++b) { cursor[b] = off; off += histG[b]; }
    }
}

// ---------------- scatter ----------------
__global__ __launch_bounds__(256) void k_scatter(
    const int* __restrict__ mArr, const float* __restrict__ h,
    const float* __restrict__ u, const float* __restrict__ v,
    u32* __restrict__ cursor, u64* __restrict__ recA, u64* __restrict__ recB,
    int N)
{
    __shared__ u32 lh[NBINS];
    __shared__ u32 lbase[NBINS];
    int tid = threadIdx.x;
    if (tid < NBINS) lh[tid] = 0;
    __syncthreads();

    u64 ra[4], rb[4];
    int bina[4], binb[4];
    u32 la[4], lb[4];
    bool val[4];
    int base = blockIdx.x * PTS_PER_BLOCK;
    #pragma unroll
    for (int k = 0; k < 4; ++k) {
        int p = base + tid + k * 256;
        val[k] = (p < N);
        if (val[k]) {
            int m = mArr[p];
            float hx = h[2ll * p], hy = h[2ll * p + 1];
            u32 qi = quant((hx + 1.0f) * 0.5f * (float)RES);
            u32 qj = quant((hy + 1.0f) * 0.5f * (float)RES);
            ra[k] = pack_rec(qi, qj, p, m);
            bina[k] = m * NSLICE + (int)(qi >> 18);
            la[k] = atomicAdd(&lh[bina[k]], 1u);
            u32 gi = quant(u[p] * (float)RES);
            u32 gj = quant(v[p] * (float)RES);
            rb[k] = pack_rec(gi, gj, p, m);
            binb[k] = BINS_F + m * NSLICE + (int)(gi >> 18);
            lb[k] = atomicAdd(&lh[binb[k]], 1u);
        }
    }
    __syncthreads();
    if (tid < NBINS) lbase[tid] = atomicAdd(&cursor[tid], lh[tid]);
    __syncthreads();
    #pragma unroll
    for (int k = 0; k < 4; ++k) {
        if (val[k]) {
            recA[lbase[bina[k]] + la[k]] = ra[k];
            recB[lbase[binb[k]] + lb[k]] = rb[k];
        }
    }
}

// ---------------- interp: 4 lanes per record ----------------
__global__ __launch_bounds__(256) void k_interp(
    const u64* __restrict__ rec, const f16* __restrict__ F,
    float* __restrict__ out, int halfOfs, int N)
{
    long long t = (long long)blockIdx.x * 256 + threadIdx.x;
    int q = (int)(t >> 2);
    if (q >= N) return;
    int c = (int)(t & 3);

    u64 r = rec[q];
    u32 qi = (u32)(r & 0xFFFFFu);
    u32 qj = (u32)((r >> 20) & 0xFFFFFu);
    u32 pm = (u32)(r >> 40);
    int p = (int)(pm & 0x1FFFFFu);
    int m = (int)(pm >> 21);

    int i1 = (int)(qi >> 11), j1 = (int)(qj >> 11);
    float ir = (float)(qi & 2047u) * (1.0f / 2048.0f);
    float jr = (float)(qj & 2047u) * (1.0f / 2048.0f);
    int i2 = (i1 + 1 == RES) ? 0 : i1 + 1;
    int j2 = (j1 + 1 == RES) ? 0 : j1 + 1;

    const f16* __restrict__ Fb = F + (long long)m * PLANE_STRIDE + c * 4;
    f16x4 h00 = *reinterpret_cast<const f16x4*>(Fb + (i1 * RES + j1) * LCH);
    f16x4 h10 = *reinterpret_cast<const f16x4*>(Fb + (i2 * RES + j1) * LCH);
    f16x4 h01 = *reinterpret_cast<const f16x4*>(Fb + (i1 * RES + j2) * LCH);
    f16x4 h11 = *reinterpret_cast<const f16x4*>(Fb + (i2 * RES + j2) * LCH);

    float omi = 1.0f - ir, omj = 1.0f - jr;
    f32x4 res;
    #pragma unroll
    for (int k = 0; k < 4; ++k) {
        float g00 = (float)h00[k], g10 = (float)h10[k];
        float g01 = (float)h01[k], g11 = (float)h11[k];
        res[k] = (g00 * omi + g10 * ir) * omj + (g01 * omi + g11 * ir) * jr;
    }
    __builtin_nontemporal_store(res,
        reinterpret_cast<f32x4*>(out + (long long)p * 32 + halfOfs + c * 4));
}

// ---------------- fallback: R5 fp16 unsorted ----------------
__global__ __launch_bounds__(256) void dualbiplane_f16(
    const int* __restrict__ mArr, const float* __restrict__ h,
    const float* __restrict__ u, const float* __restrict__ v,
    const f16* __restrict__ Fxy, const f16* __restrict__ Fuv,
    float* __restrict__ out, int N)
{
    long long t = (long long)blockIdx.x * blockDim.x + threadIdx.x;
    int p = (int)(t >> 3);
    if (p >= N) return;
    int sub = (int)(t & 7);
    int mi = __builtin_nontemporal_load(mArr + p);
    float fi, fj;
    const f16* __restrict__ F;
    if (sub < 4) {
        fi = edge((__builtin_nontemporal_load(h + 2ll * p) + 1.0f) * 0.5f * (float)RES);
        fj = edge((__builtin_nontemporal_load(h + 2ll * p + 1) + 1.0f) * 0.5f * (float)RES);
        F = Fxy;
    } else {
        fi = edge(__builtin_nontemporal_load(u + p) * (float)RES);
        fj = edge(__builtin_nontemporal_load(v + p) * (float)RES);
        F = Fuv;
    }
    int i1 = (int)fi, j1 = (int)fj;
    float ir = fi - (float)i1, jr = fj - (float)j1;
    int i2 = (i1 + 1 == RES) ? 0 : i1 + 1;
    int j2 = (j1 + 1 == RES) ? 0 : j1 + 1;
    int c = (sub & 3) * 4;
    const f16* __restrict__ Fb = F + (long long)mi * PLANE_STRIDE + c;
    f16x4 h00 = *reinterpret_cast<const f16x4*>(Fb + (i1 * RES + j1) * LCH);
    f16x4 h10 = *reinterpret_cast<const f16x4*>(Fb + (i2 * RES + j1) * LCH);
    f16x4 h01 = *reinterpret_cast<const f16x4*>(Fb + (i1 * RES + j2) * LCH);
    f16x4 h11 = *reinterpret_cast<const f16x4*>(Fb + (i2 * RES + j2) * LCH);
    float omi = 1.0f - ir, omj = 1.0f - jr;
    f32x4 res;
    #pragma unroll
    for (int k = 0; k < 4; ++k) {
        float g00 = (float)h00[k], g10 = (float)h10[k];
        float g01 = (float)h01[k], g11 = (float)h11[k];
        res[k] = (g00 * omi + g10 * ir) * omj + (g01 * omi + g11 * ir) * jr;
    }
    __builtin_nontemporal_store(res, reinterpret_cast<f32x4*>(out + t * 4));
}

// ---------------- fallback: R3 f32 simple ----------------
__global__ __launch_bounds__(256) void dualbiplane_simple(
    const int* __restrict__ mArr, const float* __restrict__ h,
    const float* __restrict__ u, const float* __restrict__ v,
    const float* __restrict__ Fxy, const float* __restrict__ Fuv,
    float* __restrict__ out, int N)
{
    long long t = (long long)blockIdx.x * blockDim.x + threadIdx.x;
    int p = (int)(t >> 3);
    if (p >= N) return;
    int sub = (int)(t & 7);
    int mi = mArr[p];
    float fi, fj;
    const float* __restrict__ F;
    if (sub < 4) {
        fi = edge((h[2ll * p] + 1.0f) * 0.5f * (float)RES);
        fj = edge((h[2ll * p + 1] + 1.0f) * 0.5f * (float)RES);
        F = Fxy;
    } else {
        fi = edge(u[p] * (float)RES);
        fj = edge(v[p] * (float)RES);
        F = Fuv;
    }
    int i1 = (int)fi, j1 = (int)fj;
    float ir = fi - (float)i1, jr = fj - (float)j1;
    int i2 = (i1 + 1 == RES) ? 0 : i1 + 1;
    int j2 = (j1 + 1 == RES) ? 0 : j1 + 1;
    int c = (sub & 3) * 4;
    const float* __restrict__ Fb = F + (long long)mi * PLANE_STRIDE + c;
    f32x4 g00 = *reinterpret_cast<const f32x4*>(Fb + (i1 * RES + j1) * LCH);
    f32x4 g10 = *reinterpret_cast<const f32x4*>(Fb + (i2 * RES + j1) * LCH);
    f32x4 g01 = *reinterpret_cast<const f32x4*>(Fb + (i1 * RES + j2) * LCH);
    f32x4 g11 = *reinterpret_cast<const f32x4*>(Fb + (i2 * RES + j2) * LCH);
    float omi = 1.0f - ir, omj = 1.0f - jr;
    f32x4 res = (g00 * omi + g10 * ir) * omj + (g01 * omi + g11 * ir) * jr;
    __builtin_nontemporal_store(res, reinterpret_cast<f32x4*>(out + t * 4));
}

extern "C" void kernel_launch(void* const* d_in, const int* in_sizes, int n_in,
                              void* d_out, int out_size, void* d_ws, size_t ws_size,
                              hipStream_t stream)
{
    const int*   m   = (const int*)d_in[0];
    const float* h   = (const float*)d_in[1];
    const float* u   = (const float*)d_in[2];
    const float* v   = (const float*)d_in[3];
    const float* Fxy = (const float*)d_in[4];
    const float* Fuv = (const float*)d_in[5];
    float* out = (float*)d_out;
    int N = in_sizes[0];

    size_t recBytes = (size_t)N * 8;
    size_t offRecA  = PLANES_BYTES;
    size_t offRecB  = offRecA + recBytes;
    size_t offHist  = offRecB + recBytes;
    size_t offCur   = offHist + NBINS * 4;
    size_t needFull = offCur + NBINS * 4;

    if (ws_size >= needFull) {
        char* ws = (char*)d_ws;
        f16*  Fxy16  = (f16*)ws;
        f16*  Fuv16  = Fxy16 + PLANE_ELEMS;
        u64*  recA   = (u64*)(ws + offRecA);
        u64*  recB   = (u64*)(ws + offRecB);
        u32*  histG  = (u32*)(ws + offHist);
        u32*  cursor = (u32*)(ws + offCur);

        hipMemsetAsync(histG, 0, NBINS * 4, stream);

        unsigned convBlocks = (unsigned)((PLANE_ELEMS / 8 + 255) / 256);
        k_conv<<<convBlocks, 256, 0, stream>>>(Fxy, Fxy16, PLANE_ELEMS);
        k_conv<<<convBlocks, 256, 0, stream>>>(Fuv, Fuv16, PLANE_ELEMS);

        unsigned nb = (unsigned)((N + PTS_PER_BLOCK - 1) / PTS_PER_BLOCK);
        k_hist<<<nb, 256, 0, stream>>>(m, h, u, v, histG, N);
        k_scan<<<1, 64, 0, stream>>>(histG, cursor);
        k_scatter<<<nb, 256, 0, stream>>>(m, h, u, v, cursor, recA, recB, N);

        unsigned bi = (unsigned)(((long long)N * 4 + 255) / 256);
        k_interp<<<bi, 256, 0, stream>>>(recA, Fxy16, out, 0,  N);
        k_interp<<<bi, 256, 0, stream>>>(recB, Fuv16, out, 16, N);
    } else if (ws_size >= PLANES_BYTES) {
        f16* Fxy16 = (f16*)d_ws;
        f16* Fuv16 = Fxy16 + PLANE_ELEMS;
        unsigned convBlocks = (unsigned)((PLANE_ELEMS / 8 + 255) / 256);
        k_conv<<<convBlocks, 256, 0, stream>>>(Fxy, Fxy16, PLANE_ELEMS);
        k_conv<<<convBlocks, 256, 0, stream>>>(Fuv, Fuv16, PLANE_ELEMS);
        long long total = (long long)N * 8;
        dualbiplane_f16<<<(unsigned)((total + 255) / 256), 256, 0, stream>>>(
            m, h, u, v, Fxy16, Fuv16, out, N);
    } else {
        long long total = (long long)N * 8;
        dualbiplane_simple<<<(unsigned)((total + 255) / 256), 256, 0, stream>>>(
            m, h, u, v, Fxy, Fuv, out, N);
    }
}

// Round 7
// 193.666 us; speedup vs baseline: 3.1091x; 1.0188x over previous
//
#include <hip/hip_runtime.h>

// DualBiPlane R7: R6 pipeline minus the hipMemsetAsync graph node.
//
// R6 rocprof showed the 128-byte hist memset (fillBufferAligned) with
// dur ~155 us inside the graph - likely most of the 197 us. Zero the
// 32-counter histogram from inside k_conv (block 0; idempotent; stream
// order guarantees it completes before k_hist). No other changes.
//
// Pipeline: k_conv x2 (f32->fp16 planes, + hist zero) -> k_hist ->
// k_scan -> k_scatter (8B records binned by (m, i>>7), block-aggregated)
// -> k_interp x2 (4 lanes/record, gathers L2-resident per bin).

typedef float f32x4 __attribute__((ext_vector_type(4)));
typedef _Float16 f16;
typedef f16 f16x4 __attribute__((ext_vector_type(4)));
typedef f16 f16x8 __attribute__((ext_vector_type(8)));
typedef unsigned int u32;
typedef unsigned long long u64;

constexpr int RES = 400;
constexpr int LCH = 16;
constexpr long long PLANE_STRIDE = (long long)RES * RES * LCH;   // elems per m
constexpr long long PLANE_ELEMS  = 4 * PLANE_STRIDE;             // per family

constexpr int NSLICE = 4;             // i1 >> 7
constexpr int BINS_F = 4 * NSLICE;    // 16 bins per family
constexpr int NBINS  = 2 * BINS_F;    // 32 total (A: 0..15, B: 16..31)
constexpr int PTS_PER_BLOCK = 1024;   // 256 threads x 4 points

constexpr size_t PLANES_BYTES = (size_t)(2 * PLANE_ELEMS) * sizeof(f16); // 40.96 MB

__device__ __forceinline__ float edge(float f) {
    return (f == (float)RES) ? (float)(RES - 1) : f;
}

// quantize coords to 11-bit fixed point fraction; qi < 2^20
__device__ __forceinline__ u32 quant(float f) { return (u32)(edge(f) * 2048.0f); }

__device__ __forceinline__ u64 pack_rec(u32 qi, u32 qj, int p, int m) {
    return (u64)qi | ((u64)qj << 20) | ((u64)((u32)p | ((u32)m << 21)) << 40);
}

// ---------------- conv: f32 plane -> fp16 plane (+ zero hist) ----------------
__global__ __launch_bounds__(256) void k_conv(
    const float* __restrict__ src, f16* __restrict__ dst, long long n,
    u32* __restrict__ histG)
{
    if (blockIdx.x == 0 && threadIdx.x < NBINS) histG[threadIdx.x] = 0u;
    long long i = ((long long)blockIdx.x * 256 + threadIdx.x) * 8;
    if (i >= n) return;
    f32x4 a, b;
    a.x = __builtin_nontemporal_load(src + i);
    a.y = __builtin_nontemporal_load(src + i + 1);
    a.z = __builtin_nontemporal_load(src + i + 2);
    a.w = __builtin_nontemporal_load(src + i + 3);
    b.x = __builtin_nontemporal_load(src + i + 4);
    b.y = __builtin_nontemporal_load(src + i + 5);
    b.z = __builtin_nontemporal_load(src + i + 6);
    b.w = __builtin_nontemporal_load(src + i + 7);
    f16x8 r;
    r[0] = (f16)a.x; r[1] = (f16)a.y; r[2] = (f16)a.z; r[3] = (f16)a.w;
    r[4] = (f16)b.x; r[5] = (f16)b.y; r[6] = (f16)b.z; r[7] = (f16)b.w;
    *reinterpret_cast<f16x8*>(dst + i) = r;
}

// ---------------- hist ----------------
__global__ __launch_bounds__(256) void k_hist(
    const int* __restrict__ mArr, const float* __restrict__ h,
    const float* __restrict__ u,
    u32* __restrict__ histG, int N)
{
    __shared__ u32 lh[NBINS];
    if (threadIdx.x < NBINS) lh[threadIdx.x] = 0;
    __syncthreads();
    int base = blockIdx.x * PTS_PER_BLOCK;
    #pragma unroll
    for (int k = 0; k < 4; ++k) {
        int p = base + threadIdx.x + k * 256;
        if (p < N) {
            int m = mArr[p];
            float hx = h[2ll * p];
            u32 qi = quant((hx + 1.0f) * 0.5f * (float)RES);
            atomicAdd(&lh[m * NSLICE + (qi >> 18)], 1u);
            u32 gi = quant(u[p] * (float)RES);
            atomicAdd(&lh[BINS_F + m * NSLICE + (gi >> 18)], 1u);
        }
    }
    __syncthreads();
    if (threadIdx.x < NBINS) atomicAdd(&histG[threadIdx.x], lh[threadIdx.x]);
}

// ---------------- scan: 32 bins, two independent prefix groups ----------------
__global__ void k_scan(const u32* __restrict__ histG, u32* __restrict__ cursor)
{
    if (threadIdx.x == 0) {
        u32 off = 0;
        for (int b = 0; b < BINS_F; ++b) { cursor[b] = off; off += histG[b]; }
        off = 0;
        for (int b = BINS_F; b < NBINS; ++b) { cursor[b] = off; off += histG[b]; }
    }
}

// ---------------- scatter ----------------
__global__ __launch_bounds__(256) void k_scatter(
    const int* __restrict__ mArr, const float* __restrict__ h,
    const float* __restrict__ u, const float* __restrict__ v,
    u32* __restrict__ cursor, u64* __restrict__ recA, u64* __restrict__ recB,
    int N)
{
    __shared__ u32 lh[NBINS];
    __shared__ u32 lbase[NBINS];
    int tid = threadIdx.x;
    if (tid < NBINS) lh[tid] = 0;
    __syncthreads();

    u64 ra[4], rb[4];
    int bina[4], binb[4];
    u32 la[4], lb[4];
    bool val[4];
    int base = blockIdx.x * PTS_PER_BLOCK;
    #pragma unroll
    for (int k = 0; k < 4; ++k) {
        int p = base + tid + k * 256;
        val[k] = (p < N);
        if (val[k]) {
            int m = mArr[p];
            float hx = h[2ll * p], hy = h[2ll * p + 1];
            u32 qi = quant((hx + 1.0f) * 0.5f * (float)RES);
            u32 qj = quant((hy + 1.0f) * 0.5f * (float)RES);
            ra[k] = pack_rec(qi, qj, p, m);
            bina[k] = m * NSLICE + (int)(qi >> 18);
            la[k] = atomicAdd(&lh[bina[k]], 1u);
            u32 gi = quant(u[p] * (float)RES);
            u32 gj = quant(v[p] * (float)RES);
            rb[k] = pack_rec(gi, gj, p, m);
            binb[k] = BINS_F + m * NSLICE + (int)(gi >> 18);
            lb[k] = atomicAdd(&lh[binb[k]], 1u);
        }
    }
    __syncthreads();
    if (tid < NBINS) lbase[tid] = atomicAdd(&cursor[tid], lh[tid]);
    __syncthreads();
    #pragma unroll
    for (int k = 0; k < 4; ++k) {
        if (val[k]) {
            recA[lbase[bina[k]] + la[k]] = ra[k];
            recB[lbase[binb[k]] + lb[k]] = rb[k];
        }
    }
}

// ---------------- interp: 4 lanes per record ----------------
__global__ __launch_bounds__(256) void k_interp(
    const u64* __restrict__ rec, const f16* __restrict__ F,
    float* __restrict__ out, int halfOfs, int N)
{
    long long t = (long long)blockIdx.x * 256 + threadIdx.x;
    int q = (int)(t >> 2);
    if (q >= N) return;
    int c = (int)(t & 3);

    u64 r = rec[q];
    u32 qi = (u32)(r & 0xFFFFFu);
    u32 qj = (u32)((r >> 20) & 0xFFFFFu);
    u32 pm = (u32)(r >> 40);
    int p = (int)(pm & 0x1FFFFFu);
    int m = (int)(pm >> 21);

    int i1 = (int)(qi >> 11), j1 = (int)(qj >> 11);
    float ir = (float)(qi & 2047u) * (1.0f / 2048.0f);
    float jr = (float)(qj & 2047u) * (1.0f / 2048.0f);
    int i2 = (i1 + 1 == RES) ? 0 : i1 + 1;
    int j2 = (j1 + 1 == RES) ? 0 : j1 + 1;

    const f16* __restrict__ Fb = F + (long long)m * PLANE_STRIDE + c * 4;
    f16x4 h00 = *reinterpret_cast<const f16x4*>(Fb + (i1 * RES + j1) * LCH);
    f16x4 h10 = *reinterpret_cast<const f16x4*>(Fb + (i2 * RES + j1) * LCH);
    f16x4 h01 = *reinterpret_cast<const f16x4*>(Fb + (i1 * RES + j2) * LCH);
    f16x4 h11 = *reinterpret_cast<const f16x4*>(Fb + (i2 * RES + j2) * LCH);

    float omi = 1.0f - ir, omj = 1.0f - jr;
    f32x4 res;
    #pragma unroll
    for (int k = 0; k < 4; ++k) {
        float g00 = (float)h00[k], g10 = (float)h10[k];
        float g01 = (float)h01[k], g11 = (float)h11[k];
        res[k] = (g00 * omi + g10 * ir) * omj + (g01 * omi + g11 * ir) * jr;
    }
    __builtin_nontemporal_store(res,
        reinterpret_cast<f32x4*>(out + (long long)p * 32 + halfOfs + c * 4));
}

// ---------------- fallback: fp16 unsorted ----------------
__global__ __launch_bounds__(256) void dualbiplane_f16(
    const int* __restrict__ mArr, const float* __restrict__ h,
    const float* __restrict__ u, const float* __restrict__ v,
    const f16* __restrict__ Fxy, const f16* __restrict__ Fuv,
    float* __restrict__ out, int N)
{
    long long t = (long long)blockIdx.x * blockDim.x + threadIdx.x;
    int p = (int)(t >> 3);
    if (p >= N) return;
    int sub = (int)(t & 7);
    int mi = __builtin_nontemporal_load(mArr + p);
    float fi, fj;
    const f16* __restrict__ F;
    if (sub < 4) {
        fi = edge((__builtin_nontemporal_load(h + 2ll * p) + 1.0f) * 0.5f * (float)RES);
        fj = edge((__builtin_nontemporal_load(h + 2ll * p + 1) + 1.0f) * 0.5f * (float)RES);
        F = Fxy;
    } else {
        fi = edge(__builtin_nontemporal_load(u + p) * (float)RES);
        fj = edge(__builtin_nontemporal_load(v + p) * (float)RES);
        F = Fuv;
    }
    int i1 = (int)fi, j1 = (int)fj;
    float ir = fi - (float)i1, jr = fj - (float)j1;
    int i2 = (i1 + 1 == RES) ? 0 : i1 + 1;
    int j2 = (j1 + 1 == RES) ? 0 : j1 + 1;
    int c = (sub & 3) * 4;
    const f16* __restrict__ Fb = F + (long long)mi * PLANE_STRIDE + c;
    f16x4 h00 = *reinterpret_cast<const f16x4*>(Fb + (i1 * RES + j1) * LCH);
    f16x4 h10 = *reinterpret_cast<const f16x4*>(Fb + (i2 * RES + j1) * LCH);
    f16x4 h01 = *reinterpret_cast<const f16x4*>(Fb + (i1 * RES + j2) * LCH);
    f16x4 h11 = *reinterpret_cast<const f16x4*>(Fb + (i2 * RES + j2) * LCH);
    float omi = 1.0f - ir, omj = 1.0f - jr;
    f32x4 res;
    #pragma unroll
    for (int k = 0; k < 4; ++k) {
        float g00 = (float)h00[k], g10 = (float)h10[k];
        float g01 = (float)h01[k], g11 = (float)h11[k];
        res[k] = (g00 * omi + g10 * ir) * omj + (g01 * omi + g11 * ir) * jr;
    }
    __builtin_nontemporal_store(res, reinterpret_cast<f32x4*>(out + t * 4));
}

// ---------------- fallback: f32 simple ----------------
__global__ __launch_bounds__(256) void dualbiplane_simple(
    const int* __restrict__ mArr, const float* __restrict__ h,
    const float* __restrict__ u, const float* __restrict__ v,
    const float* __restrict__ Fxy, const float* __restrict__ Fuv,
    float* __restrict__ out, int N)
{
    long long t = (long long)blockIdx.x * blockDim.x + threadIdx.x;
    int p = (int)(t >> 3);
    if (p >= N) return;
    int sub = (int)(t & 7);
    int mi = mArr[p];
    float fi, fj;
    const float* __restrict__ F;
    if (sub < 4) {
        fi = edge((h[2ll * p] + 1.0f) * 0.5f * (float)RES);
        fj = edge((h[2ll * p + 1] + 1.0f) * 0.5f * (float)RES);
        F = Fxy;
    } else {
        fi = edge(u[p] * (float)RES);
        fj = edge(v[p] * (float)RES);
        F = Fuv;
    }
    int i1 = (int)fi, j1 = (int)fj;
    float ir = fi - (float)i1, jr = fj - (float)j1;
    int i2 = (i1 + 1 == RES) ? 0 : i1 + 1;
    int j2 = (j1 + 1 == RES) ? 0 : j1 + 1;
    int c = (sub & 3) * 4;
    const float* __restrict__ Fb = F + (long long)mi * PLANE_STRIDE + c;
    f32x4 g00 = *reinterpret_cast<const f32x4*>(Fb + (i1 * RES + j1) * LCH);
    f32x4 g10 = *reinterpret_cast<const f32x4*>(Fb + (i2 * RES + j1) * LCH);
    f32x4 g01 = *reinterpret_cast<const f32x4*>(Fb + (i1 * RES + j2) * LCH);
    f32x4 g11 = *reinterpret_cast<const f32x4*>(Fb + (i2 * RES + j2) * LCH);
    float omi = 1.0f - ir, omj = 1.0f - jr;
    f32x4 res = (g00 * omi + g10 * ir) * omj + (g01 * omi + g11 * ir) * jr;
    __builtin_nontemporal_store(res, reinterpret_cast<f32x4*>(out + t * 4));
}

extern "C" void kernel_launch(void* const* d_in, const int* in_sizes, int n_in,
                              void* d_out, int out_size, void* d_ws, size_t ws_size,
                              hipStream_t stream)
{
    const int*   m   = (const int*)d_in[0];
    const float* h   = (const float*)d_in[1];
    const float* u   = (const float*)d_in[2];
    const float* v   = (const float*)d_in[3];
    const float* Fxy = (const float*)d_in[4];
    const float* Fuv = (const float*)d_in[5];
    float* out = (float*)d_out;
    int N = in_sizes[0];

    size_t recBytes = (size_t)N * 8;
    size_t offRecA  = PLANES_BYTES;
    size_t offRecB  = offRecA + recBytes;
    size_t offHist  = offRecB + recBytes;
    size_t offCur   = offHist + NBINS * 4;
    size_t needFull = offCur + NBINS * 4;

    if (ws_size >= needFull) {
        char* ws = (char*)d_ws;
        f16*  Fxy16  = (f16*)ws;
        f16*  Fuv16  = Fxy16 + PLANE_ELEMS;
        u64*  recA   = (u64*)(ws + offRecA);
        u64*  recB   = (u64*)(ws + offRecB);
        u32*  histG  = (u32*)(ws + offHist);
        u32*  cursor = (u32*)(ws + offCur);

        unsigned convBlocks = (unsigned)((PLANE_ELEMS / 8 + 255) / 256);
        k_conv<<<convBlocks, 256, 0, stream>>>(Fxy, Fxy16, PLANE_ELEMS, histG);
        k_conv<<<convBlocks, 256, 0, stream>>>(Fuv, Fuv16, PLANE_ELEMS, histG);

        unsigned nb = (unsigned)((N + PTS_PER_BLOCK - 1) / PTS_PER_BLOCK);
        k_hist<<<nb, 256, 0, stream>>>(m, h, u, histG, N);
        k_scan<<<1, 64, 0, stream>>>(histG, cursor);
        k_scatter<<<nb, 256, 0, stream>>>(m, h, u, v, cursor, recA, recB, N);

        unsigned bi = (unsigned)(((long long)N * 4 + 255) / 256);
        k_interp<<<bi, 256, 0, stream>>>(recA, Fxy16, out, 0,  N);
        k_interp<<<bi, 256, 0, stream>>>(recB, Fuv16, out, 16, N);
    } else if (ws_size >= PLANES_BYTES) {
        f16* Fxy16 = (f16*)d_ws;
        f16* Fuv16 = Fxy16 + PLANE_ELEMS;
        // histG unused in this path; point it at the end of the planes if room,
        // else reuse plane memory is unsafe -> give it a dummy inside planes?
        // Simplest: small static fallback zero target is not needed because
        // k_hist never runs here; but k_conv still writes 128 B. Give it the
        // first 128 B AFTER planes if available, else skip sort path anyway.
        u32* dummy = (u32*)(Fxy16);  // overwritten by conv itself afterwards:
        // NOT safe in general; instead just run convs without hist zeroing by
        // passing a scratch region: planes path requires ws >= PLANES_BYTES;
        // if there is no extra room, reuse the last 128 B of the fp16 planes
        // region is wrong. Use d_out start instead: it is overwritten later
        // by the interp... but fallback path writes all of d_out too, in the
        // same kernel AFTER conv. Safe: conv writes histG=d_out[0..31] first,
        // then dualbiplane_f16 overwrites every d_out element.
        dummy = (u32*)out;
        unsigned convBlocks = (unsigned)((PLANE_ELEMS / 8 + 255) / 256);
        k_conv<<<convBlocks, 256, 0, stream>>>(Fxy, Fxy16, PLANE_ELEMS, dummy);
        k_conv<<<convBlocks, 256, 0, stream>>>(Fuv, Fuv16, PLANE_ELEMS, dummy);
        long long total = (long long)N * 8;
        dualbiplane_f16<<<(unsigned)((total + 255) / 256), 256, 0, stream>>>(
            m, h, u, v, Fxy16, Fuv16, out, N);
    } else {
        long long total = (long long)N * 8;
        dualbiplane_simple<<<(unsigned)((total + 255) / 256), 256, 0, stream>>>(
            m, h, u, v, Fxy, Fuv, out, N);
    }
}